// Round 27
// baseline (296.913 us; speedup 1.0000x reference)
//
#include <hip/hip_runtime.h>

#define NROWS 65536
#define DDIM  256
#define KCODES 1024
#define MARGIN 0.05f        // bulk ambiguity threshold (>> split error + window)
#define TIE_WINDOW 8.0e-5   // proven r11/r12

typedef __attribute__((ext_vector_type(8))) short bf16x8;
typedef __attribute__((ext_vector_type(4))) float f32x4;

union F4 { float4 v; float f[4]; };

__device__ __forceinline__ unsigned bf16rne(float f) {
    unsigned u = __float_as_uint(f);
    return (u + 0x7fffu + ((u >> 16) & 1u)) >> 16;
}
__device__ __forceinline__ float bf16tof(unsigned h) {
    return __uint_as_float(h << 16);
}

// ---- kernel 0: per-code-row c2 (f32+f64) AND fragment write (merged) ----
// block = code row c; lane handles k = lane*4 .. +3.
// frag short-index = ((ntg*8+ks)*64 + laneS)*8 + j0, laneS = ((k>>3)&3)*16 + (c&15)
// (algebra identical to the proven prep_frags mapping).
__global__ __launch_bounds__(64) void c2prep(const float* __restrict__ cb,
                                             float* __restrict__ c2f,
                                             double* __restrict__ c2d,
                                             unsigned short* __restrict__ fh,
                                             unsigned short* __restrict__ fl) {
    const int c = blockIdx.x, lane = threadIdx.x;
    F4 v; v.v = reinterpret_cast<const float4*>(cb + (size_t)c * DDIM)[lane];
    double s = (double)v.f[0] * v.f[0] + (double)v.f[1] * v.f[1]
             + (double)v.f[2] * v.f[2] + (double)v.f[3] * v.f[3];
    #pragma unroll
    for (int off = 32; off; off >>= 1) s += __shfl_xor(s, off);
    if (lane == 0) { c2d[c] = s; c2f[c] = (float)s; }

    const int k  = lane * 4;
    const int ks = k >> 5, g = (k >> 3) & 3, j0 = k & 7;   // j0 in {0,4}
    const int laneS = g * 16 + (c & 15);
    const int ntg   = c >> 4;
    const size_t h16 = (((size_t)(ntg * 8 + ks) * 64 + laneS) * 8 + j0);
    unsigned h0 = bf16rne(v.f[0]), h1 = bf16rne(v.f[1]),
             h2 = bf16rne(v.f[2]), h3 = bf16rne(v.f[3]);
    unsigned l0 = bf16rne(v.f[0] - bf16tof(h0)), l1 = bf16rne(v.f[1] - bf16tof(h1)),
             l2 = bf16rne(v.f[2] - bf16tof(h2)), l3 = bf16rne(v.f[3] - bf16tof(h3));
    unsigned* ph = reinterpret_cast<unsigned*>(fh + h16);
    unsigned* pl = reinterpret_cast<unsigned*>(fl + h16);
    ph[0] = h0 | (h1 << 16); ph[1] = h2 | (h3 << 16);
    pl[0] = l0 | (l1 << 16); pl[1] = l2 | (l3 << 16);
}

// ---- kernel 1: MFMA bulk (r19 structure) + sign-encoded flag in rowsq ----
__global__ __launch_bounds__(512) void vqmfma(const float* __restrict__ x,
                                              const unsigned short* __restrict__ fbh,
                                              const unsigned short* __restrict__ fbl,
                                              const float* __restrict__ c2f,
                                              float* __restrict__ out_idx,
                                              float* __restrict__ rowsq) {
    __shared__ bf16x8 lds_ah[1024];    // [rt 2][ks 8][lane 64] -> 16 KB
    __shared__ bf16x8 lds_al[1024];    // 16 KB
    __shared__ float  lds_c2[KCODES];  // 4 KB
    __shared__ float  m_b1[256]; __shared__ float m_b2[256]; __shared__ int m_i1[256];
    __shared__ float  x2s[32];

    const int tid  = threadIdx.x;
    const int w    = tid >> 6;          // 0..7 = code group (32 codes each/chunk)
    const int lane = tid & 63;
    const int row0 = blockIdx.x * 32;

    #pragma unroll
    for (int q = 0; q < 2; q++) lds_c2[q * 512 + tid] = c2f[q * 512 + tid];

    // stage x tile (32 rows) -> hi/lo fragments in LDS; x2 free per row
    {
        const float4* gx = reinterpret_cast<const float4*>(x + (size_t)row0 * DDIM);
        unsigned* pah = reinterpret_cast<unsigned*>(lds_ah);
        unsigned* pal = reinterpret_cast<unsigned*>(lds_al);
        #pragma unroll
        for (int jj = 0; jj < 4; jj++) {
            int flat4 = jj * 512 + tid;
            int r = flat4 >> 6;                  // row = jj*8 + w (one row/wave)
            int k = (flat4 & 63) * 4;
            F4 v; v.v = gx[flat4];
            float sq = v.f[0]*v.f[0] + v.f[1]*v.f[1] + v.f[2]*v.f[2] + v.f[3]*v.f[3];
            #pragma unroll
            for (int off = 32; off; off >>= 1) sq += __shfl_xor(sq, off);
            if (lane == 0) x2s[r] = sq;
            int rt = r >> 4, row = r & 15;
            int ks = k >> 5, gg = (k >> 3) & 3, j0 = k & 7;   // j0 in {0,4}
            int laneS = gg * 16 + row;
            int u32i = ((((rt * 8 + ks) * 64 + laneS) * 8 + j0) >> 1);
            unsigned h0 = bf16rne(v.f[0]), h1 = bf16rne(v.f[1]),
                     h2 = bf16rne(v.f[2]), h3 = bf16rne(v.f[3]);
            pah[u32i]     = h0 | (h1 << 16);
            pah[u32i + 1] = h2 | (h3 << 16);
            unsigned l0 = bf16rne(v.f[0] - bf16tof(h0)), l1 = bf16rne(v.f[1] - bf16tof(h1)),
                     l2 = bf16rne(v.f[2] - bf16tof(h2)), l3 = bf16rne(v.f[3] - bf16tof(h3));
            pal[u32i]     = l0 | (l1 << 16);
            pal[u32i + 1] = l2 | (l3 << 16);
        }
    }
    __syncthreads();

    float bestv[8], secv[8]; int besti[8];
    #pragma unroll
    for (int e = 0; e < 8; e++) { bestv[e] = 1e30f; secv[e] = 1e30f; besti[e] = 0; }

    const bf16x8* Bh = reinterpret_cast<const bf16x8*>(fbh);
    const bf16x8* Bl = reinterpret_cast<const bf16x8*>(fbl);

    for (int cc = 0; cc < KCODES; cc += 256) {
        f32x4 acc[2][2];
        #pragma unroll
        for (int rt = 0; rt < 2; rt++)
            #pragma unroll
            for (int nt = 0; nt < 2; nt++) acc[rt][nt] = (f32x4){0.f, 0.f, 0.f, 0.f};

        const int ntg0 = (cc >> 4) + w * 2;
        const bf16x8* b0h = Bh + (size_t)(ntg0 * 8) * 64 + lane;
        const bf16x8* b0l = Bl + (size_t)(ntg0 * 8) * 64 + lane;
        const bf16x8* b1h = b0h + 8 * 64;
        const bf16x8* b1l = b0l + 8 * 64;
        const bf16x8* a0  = &lds_ah[lane];
        const bf16x8* a1  = &lds_ah[8 * 64 + lane];
        const bf16x8* a0l = &lds_al[lane];
        const bf16x8* a1l = &lds_al[8 * 64 + lane];

        #pragma unroll
        for (int ks = 0; ks < 8; ks++) {
            bf16x8 ah0 = a0[ks * 64],  ah1 = a1[ks * 64];
            bf16x8 al0 = a0l[ks * 64], al1 = a1l[ks * 64];
            bf16x8 bh0 = b0h[ks * 64], bl0 = b0l[ks * 64];
            bf16x8 bh1 = b1h[ks * 64], bl1 = b1l[ks * 64];
            acc[0][0] = __builtin_amdgcn_mfma_f32_16x16x32_bf16(ah0, bh0, acc[0][0], 0, 0, 0);
            acc[1][0] = __builtin_amdgcn_mfma_f32_16x16x32_bf16(ah1, bh0, acc[1][0], 0, 0, 0);
            acc[0][1] = __builtin_amdgcn_mfma_f32_16x16x32_bf16(ah0, bh1, acc[0][1], 0, 0, 0);
            acc[1][1] = __builtin_amdgcn_mfma_f32_16x16x32_bf16(ah1, bh1, acc[1][1], 0, 0, 0);
            acc[0][0] = __builtin_amdgcn_mfma_f32_16x16x32_bf16(ah0, bl0, acc[0][0], 0, 0, 0);
            acc[1][0] = __builtin_amdgcn_mfma_f32_16x16x32_bf16(ah1, bl0, acc[1][0], 0, 0, 0);
            acc[0][1] = __builtin_amdgcn_mfma_f32_16x16x32_bf16(ah0, bl1, acc[0][1], 0, 0, 0);
            acc[1][1] = __builtin_amdgcn_mfma_f32_16x16x32_bf16(ah1, bl1, acc[1][1], 0, 0, 0);
            acc[0][0] = __builtin_amdgcn_mfma_f32_16x16x32_bf16(al0, bh0, acc[0][0], 0, 0, 0);
            acc[1][0] = __builtin_amdgcn_mfma_f32_16x16x32_bf16(al1, bh0, acc[1][0], 0, 0, 0);
            acc[0][1] = __builtin_amdgcn_mfma_f32_16x16x32_bf16(al0, bh1, acc[0][1], 0, 0, 0);
            acc[1][1] = __builtin_amdgcn_mfma_f32_16x16x32_bf16(al1, bh1, acc[1][1], 0, 0, 0);
        }
        #pragma unroll
        for (int nt = 0; nt < 2; nt++) {
            int c = cc + w * 32 + nt * 16 + (lane & 15);
            float c2v = lds_c2[c];
            #pragma unroll
            for (int rt = 0; rt < 2; rt++)
                #pragma unroll
                for (int reg = 0; reg < 4; reg++) {
                    float s = __fmaf_rn(-2.f, acc[rt][nt][reg], c2v);
                    int e = rt * 4 + reg;
                    if (s < bestv[e]) { secv[e] = bestv[e]; bestv[e] = s; besti[e] = c; }
                    else if (s < secv[e]) secv[e] = s;
                }
        }
    }

    // merge across the 16 lanes sharing a row
    #pragma unroll
    for (int e = 0; e < 8; e++) {
        float b1 = bestv[e]; int i1 = besti[e]; float b2 = secv[e];
        #pragma unroll
        for (int off = 8; off; off >>= 1) {
            float o1 = __shfl_xor(b1, off, 16);
            int   oi = __shfl_xor(i1, off, 16);
            float o2 = __shfl_xor(b2, off, 16);
            if (o1 < b1 || (o1 == b1 && oi < i1)) { b2 = fminf(b1, o2); b1 = o1; i1 = oi; }
            else                                  { b2 = fminf(o1, b2); }
        }
        if ((lane & 15) == 0) {
            int rt = e >> 2, reg = e & 3;
            int rib = rt * 16 + (lane >> 4) * 4 + reg;  // row in block (0..31)
            m_b1[w * 32 + rib] = b1; m_i1[w * 32 + rib] = i1; m_b2[w * 32 + rib] = b2;
        }
    }
    __syncthreads();

    // cross-wave merge + idx + sign-encoded rowsq (negative => ambiguous)
    if (tid < 32) {
        float b1 = m_b1[tid]; int i1 = m_i1[tid]; float b2 = m_b2[tid];
        #pragma unroll
        for (int ww = 1; ww < 8; ww++) {
            float o1 = m_b1[ww * 32 + tid]; int oi = m_i1[ww * 32 + tid];
            float o2 = m_b2[ww * 32 + tid];
            if (o1 < b1 || (o1 == b1 && oi < i1)) { b2 = fminf(b1, o2); b1 = o1; i1 = oi; }
            else                                  { b2 = fminf(o1, b2); }
        }
        out_idx[row0 + tid] = (float)i1;
        float d2b = b1 + x2s[tid];              // d2 ~ 250+, never near 0
        rowsq[row0 + tid] = (b2 - b1 < MARGIN) ? -d2b : d2b;
    }
}

// ---- kernel 2: finalize = refine(flagged) + gather out_q + loss partial ----
__global__ __launch_bounds__(256) void finalize(const float* __restrict__ x,
                                                const float* __restrict__ cb,
                                                const double* __restrict__ c2d,
                                                float* __restrict__ out_idx,
                                                float* __restrict__ rowsq,
                                                float* __restrict__ out_q,
                                                float* __restrict__ partial) {
    __shared__ double xs[DDIM];
    __shared__ double redd[256];
    __shared__ int    redi[256];
    __shared__ int    sbest[32];
    __shared__ float  ssq[32];

    const int tid  = threadIdx.x;
    const int row0 = blockIdx.x * 32;

    if (tid < 32) {
        sbest[tid] = (int)out_idx[row0 + tid];
        ssq[tid]   = rowsq[row0 + tid];
    }
    __syncthreads();

    // phase 1: exact-f64 window-argmin for ambiguous rows (uniform branch)
    for (int r = 0; r < 32; r++) {
        if (!(ssq[r] < 0.f)) continue;          // uniform across block
        const int row = row0 + r;
        const double xv = (double)x[(size_t)row * DDIM + tid];
        xs[tid] = xv;
        redd[tid] = xv * xv;
        __syncthreads();
        for (int off = 128; off; off >>= 1) {
            if (tid < off) redd[tid] += redd[tid + off];
            __syncthreads();
        }
        const double x2 = redd[0];
        __syncthreads();
        double d2v[4];
        #pragma unroll
        for (int j = 0; j < 4; j++) {
            const int c = tid + 256 * j;
            const float* cp = cb + (size_t)c * DDIM;
            double dot = 0.0;
            for (int d = 0; d < DDIM; d += 4) {
                F4 cv; cv.v = *reinterpret_cast<const float4*>(cp + d);
                dot += xs[d+0]*(double)cv.f[0] + xs[d+1]*(double)cv.f[1]
                     + xs[d+2]*(double)cv.f[2] + xs[d+3]*(double)cv.f[3];
            }
            d2v[j] = x2 - 2.0 * dot + c2d[c];
        }
        double mv = fmin(fmin(d2v[0], d2v[1]), fmin(d2v[2], d2v[3]));
        redd[tid] = mv;
        __syncthreads();
        for (int off = 128; off; off >>= 1) {
            if (tid < off) redd[tid] = fmin(redd[tid], redd[tid + off]);
            __syncthreads();
        }
        const double d2min = redd[0];
        const double thr = d2min + TIE_WINDOW;
        __syncthreads();
        int ci = 0x7fffffff;
        #pragma unroll
        for (int j = 0; j < 4; j++)
            if (d2v[j] <= thr) ci = min(ci, tid + 256 * j);
        redi[tid] = ci;
        __syncthreads();
        for (int off = 128; off; off >>= 1) {
            if (tid < off) redi[tid] = min(redi[tid], redi[tid + off]);
            __syncthreads();
        }
        if (tid == 0) {
            sbest[r] = redi[0];
            ssq[r]   = (float)d2min;            // within TIE_WINDOW of winner
            out_idx[row] = (float)redi[0];
        }
        __syncthreads();
    }
    __syncthreads();

    // phase 2: gather out_q (cb L2-hot) — 8 threads/row
    {
        const int r  = tid >> 3;
        const int d0 = (tid & 7) * 32;
        const int bi = sbest[r];
        const float4* gq = reinterpret_cast<const float4*>(cb + (size_t)bi * DDIM + d0);
        float4* go = reinterpret_cast<float4*>(out_q + (size_t)(row0 + r) * DDIM + d0);
        #pragma unroll
        for (int j = 0; j < 8; j++) go[j] = gq[j];
    }

    // phase 3: block partial of rowsq
    if (tid < 32) {
        float s = ssq[tid];
        #pragma unroll
        for (int off = 16; off; off >>= 1) s += __shfl_xor(s, off, 32);
        if (tid == 0) partial[blockIdx.x] = s;
    }
}

// ---- kernel 3: loss from 2048 block partials ----
__global__ __launch_bounds__(256) void loss_kernel(const float* __restrict__ partial,
                                                   float* __restrict__ out_loss) {
    __shared__ float w[4];
    float s = 0.f;
    for (int j = threadIdx.x; j < 2048; j += 256) s += partial[j];
    #pragma unroll
    for (int off = 32; off; off >>= 1) s += __shfl_down(s, off);
    if ((threadIdx.x & 63) == 0) w[threadIdx.x >> 6] = s;
    __syncthreads();
    if (threadIdx.x == 0)
        out_loss[0] = 1.25f * (w[0] + w[1] + w[2] + w[3]) / 16777216.f;
}

extern "C" void kernel_launch(void* const* d_in, const int* in_sizes, int n_in,
                              void* d_out, int out_size, void* d_ws, size_t ws_size,
                              hipStream_t stream) {
    const float* x  = (const float*)d_in[0];
    const float* cb = (const float*)d_in[1];
    float* out      = (float*)d_out;
    float* out_q    = out;                       // 16777216 floats
    float* out_loss = out + 16777216;            // 1 float
    float* out_idx  = out + 16777217;            // 65536 floats

    // ws layout: 1.33 MB total (< 1.36 MB proven available in r23/r24 Path A)
    char* wsp = (char*)d_ws;
    float*  ws_c2f     = (float*) (wsp +      0);   //  4 KB
    double* ws_c2d     = (double*)(wsp +   4096);   //  8 KB  -> 12288
    float*  ws_rowsq   = (float*) (wsp +  12288);   // 256 KB -> 274432
    float*  ws_partial = (float*) (wsp + 274432);   //  8 KB  -> 282624
    unsigned short* ws_fbh = (unsigned short*)(wsp + 282624);  // 512 KB -> 806912
    unsigned short* ws_fbl = ws_fbh + 262144;                  // 512 KB -> 1331200

    c2prep<<<KCODES, 64, 0, stream>>>(cb, ws_c2f, ws_c2d, ws_fbh, ws_fbl);
    vqmfma<<<NROWS / 32, 512, 0, stream>>>(x, ws_fbh, ws_fbl, ws_c2f,
                                           out_idx, ws_rowsq);
    finalize<<<NROWS / 32, 256, 0, stream>>>(x, cb, ws_c2d, out_idx,
                                             ws_rowsq, out_q, ws_partial);
    loss_kernel<<<1, 256, 0, stream>>>(ws_partial, out_loss);
}